// Round 1
// baseline (434.206 us; speedup 1.0000x reference)
//
#include <hip/hip_runtime.h>

#define N_ROWS 65536
#define DIM    1024
#define KCL    256

typedef __bf16 bf16_t;
typedef __attribute__((ext_vector_type(8))) __bf16 bf16x8;
typedef __attribute__((ext_vector_type(4))) __bf16 bf16x4;
typedef __attribute__((ext_vector_type(4))) float  floatx4;

// ---------------- P0: clusters -> bf16, c_sq ----------------
__global__ __launch_bounds__(256)
void prep_clusters(const float* __restrict__ clusters,
                   bf16_t* __restrict__ cb, float* __restrict__ c_sq) {
    const int k = blockIdx.x;     // 0..255
    const int t = threadIdx.x;    // 0..255
    const float4 v = ((const float4*)(clusters + (size_t)k * DIM))[t];
    bf16x4 b;
    b[0] = (bf16_t)v.x; b[1] = (bf16_t)v.y; b[2] = (bf16_t)v.z; b[3] = (bf16_t)v.w;
    *(bf16x4*)(cb + (size_t)k * DIM + t * 4) = b;
    float s = v.x*v.x + v.y*v.y + v.z*v.z + v.w*v.w;
    #pragma unroll
    for (int m = 1; m < 64; m <<= 1) s += __shfl_xor(s, m);
    __shared__ float ps[4];
    if ((t & 63) == 0) ps[t >> 6] = s;
    __syncthreads();
    if (t == 0) c_sq[k] = ps[0] + ps[1] + ps[2] + ps[3];
}

// ---------------- P1: GEMM + q epilogue ----------------
// Block: 512 threads = 8 waves, tile 128(M) x 256(N=all K clusters), BK=64.
// Wave w: rows (w>>2)*64..+64, cols (w&3)*64..+64 -> 4x4 tiles of 16x16x32 MFMA.
__global__ __launch_bounds__(512, 2)
void gemm_q(const float* __restrict__ x, const bf16_t* __restrict__ cb,
            const float* __restrict__ c_sq, float* __restrict__ q_out,
            float* __restrict__ q_sum) {
    __shared__ bf16_t As[128 * 72];   // padded stride 72 (bank-conflict break)
    __shared__ bf16_t Bs[256 * 72];
    __shared__ float  xsq[128];
    __shared__ float  rowsum[128];
    __shared__ float  colsum[256];

    const int tid  = threadIdx.x;
    const int lane = tid & 63;
    const int w    = tid >> 6;          // 0..7
    const int l15  = lane & 15;
    const int quad = lane >> 4;         // 0..3
    const int wm   = (w >> 2) * 64;     // 0 or 64
    const int wn   = (w & 3) * 64;      // 0,64,128,192
    const int block_row = blockIdx.x * 128;

    if (tid < 128) { xsq[tid] = 0.f; rowsum[tid] = 0.f; }
    if (tid < 256) colsum[tid] = 0.f;

    floatx4 acc[4][4];
    #pragma unroll
    for (int i = 0; i < 4; i++)
        #pragma unroll
        for (int j = 0; j < 4; j++) {
            floatx4 z = {0.f, 0.f, 0.f, 0.f};
            acc[i][j] = z;
        }

    __syncthreads();

    for (int kb = 0; kb < 16; ++kb) {
        const int k0 = kb * 64;
        // --- stage A (fp32 x -> bf16 LDS), 128x64 tile ---
        float4 av[4];
        #pragma unroll
        for (int i = 0; i < 4; i++) {
            int f = tid + i * 512;          // float4 index in 128x16 grid
            int r = f >> 4, c4 = f & 15;
            av[i] = *(const float4*)(x + (size_t)(block_row + r) * DIM + k0 + c4 * 4);
        }
        // --- stage B (bf16 clusters), 256x64 tile ---
        bf16x8 bv[4];
        #pragma unroll
        for (int i = 0; i < 4; i++) {
            int g = tid + i * 512;          // 8-elem chunk index in 256x8 grid
            int r = g >> 3, c8 = g & 7;
            bv[i] = *(const bf16x8*)(cb + (size_t)r * DIM + k0 + c8 * 8);
        }
        // --- x_sq partial accumulation (fp32, from staged data) ---
        #pragma unroll
        for (int i = 0; i < 4; i++) {
            float s = av[i].x*av[i].x + av[i].y*av[i].y + av[i].z*av[i].z + av[i].w*av[i].w;
            s += __shfl_xor(s, 1); s += __shfl_xor(s, 2);
            s += __shfl_xor(s, 4); s += __shfl_xor(s, 8);
            if (l15 == 0) atomicAdd(&xsq[(tid + i * 512) >> 4], s);
        }
        // --- LDS writes ---
        #pragma unroll
        for (int i = 0; i < 4; i++) {
            int f = tid + i * 512;
            int r = f >> 4, c4 = f & 15;
            bf16x4 b;
            b[0] = (bf16_t)av[i].x; b[1] = (bf16_t)av[i].y;
            b[2] = (bf16_t)av[i].z; b[3] = (bf16_t)av[i].w;
            *(bf16x4*)(As + r * 72 + c4 * 4) = b;
        }
        #pragma unroll
        for (int i = 0; i < 4; i++) {
            int g = tid + i * 512;
            int r = g >> 3, c8 = g & 7;
            *(bf16x8*)(Bs + r * 72 + c8 * 8) = bv[i];
        }
        __syncthreads();
        // --- MFMA: 2 k-steps x 4x4 tiles ---
        #pragma unroll
        for (int kk = 0; kk < 2; ++kk) {
            bf16x8 af[4], bfr[4];
            #pragma unroll
            for (int mt = 0; mt < 4; ++mt)
                af[mt] = *(bf16x8*)(As + (wm + mt * 16 + l15) * 72 + kk * 32 + quad * 8);
            #pragma unroll
            for (int nt = 0; nt < 4; ++nt)
                bfr[nt] = *(bf16x8*)(Bs + (wn + nt * 16 + l15) * 72 + kk * 32 + quad * 8);
            #pragma unroll
            for (int mt = 0; mt < 4; ++mt)
                #pragma unroll
                for (int nt = 0; nt < 4; ++nt)
                    acc[mt][nt] = __builtin_amdgcn_mfma_f32_16x16x32_bf16(
                        af[mt], bfr[nt], acc[mt][nt], 0, 0, 0);
        }
        __syncthreads();
    }

    // ---- epilogue: dist -> q_un -> row-normalize -> store + column sums ----
    float csq_v[4];
    #pragma unroll
    for (int nt = 0; nt < 4; nt++) csq_v[nt] = c_sq[wn + nt * 16 + l15];
    floatx4 xs4[4];
    #pragma unroll
    for (int mt = 0; mt < 4; mt++)
        xs4[mt] = *(floatx4*)(xsq + wm + mt * 16 + quad * 4);

    #pragma unroll
    for (int mt = 0; mt < 4; mt++) {
        floatx4 rps = {0.f, 0.f, 0.f, 0.f};
        #pragma unroll
        for (int nt = 0; nt < 4; nt++) {
            #pragma unroll
            for (int r = 0; r < 4; r++) {
                float d  = xs4[mt][r] + csq_v[nt] - 2.0f * acc[mt][nt][r];
                float qv = 1.0f / (1.0f + d);   // ALPHA = 1
                acc[mt][nt][r] = qv;
                rps[r] += qv;
            }
        }
        #pragma unroll
        for (int m = 1; m < 16; m <<= 1) {
            rps[0] += __shfl_xor(rps[0], m);
            rps[1] += __shfl_xor(rps[1], m);
            rps[2] += __shfl_xor(rps[2], m);
            rps[3] += __shfl_xor(rps[3], m);
        }
        if (l15 == 0) {
            #pragma unroll
            for (int r = 0; r < 4; r++)
                atomicAdd(&rowsum[wm + mt * 16 + quad * 4 + r], rps[r]);
        }
    }
    __syncthreads();

    float colp[4] = {0.f, 0.f, 0.f, 0.f};
    #pragma unroll
    for (int mt = 0; mt < 4; mt++) {
        floatx4 rs4 = *(floatx4*)(rowsum + wm + mt * 16 + quad * 4);
        floatx4 inv;
        #pragma unroll
        for (int r = 0; r < 4; r++) inv[r] = 1.0f / rs4[r];
        #pragma unroll
        for (int nt = 0; nt < 4; nt++) {
            #pragma unroll
            for (int r = 0; r < 4; r++) {
                float qn = acc[mt][nt][r] * inv[r];
                q_out[(size_t)(block_row + wm + mt * 16 + quad * 4 + r) * KCL
                      + wn + nt * 16 + l15] = qn;
                colp[nt] += qn;
            }
        }
    }
    #pragma unroll
    for (int nt = 0; nt < 4; nt++) {
        colp[nt] += __shfl_xor(colp[nt], 16);
        colp[nt] += __shfl_xor(colp[nt], 32);
    }
    if (lane < 16) {
        #pragma unroll
        for (int nt = 0; nt < 4; nt++)
            atomicAdd(&colsum[wn + nt * 16 + l15], colp[nt]);
    }
    __syncthreads();
    if (tid < 256) atomicAdd(&q_sum[tid], colsum[tid]);
}

// ---------------- P2: sharpen + threshold + scatter ----------------
// One wave per row. q_ = (q^2/q_sum) row-normalized; keep argmax; >0.1 hard gate.
__global__ __launch_bounds__(256)
void sharpen_scatter(const float* __restrict__ q, const float* __restrict__ q_sum,
                     const float* __restrict__ x,
                     float* __restrict__ numer, float* __restrict__ denom) {
    const int tid  = threadIdx.x;
    const int lane = tid & 63;
    const int row  = blockIdx.x * 4 + (tid >> 6);
    const float4 q4 = ((const float4*)(q + (size_t)row * KCL))[lane];
    const float4 s4 = ((const float4*)q_sum)[lane];
    float tx = q4.x * q4.x / s4.x;
    float ty = q4.y * q4.y / s4.y;
    float tz = q4.z * q4.z / s4.z;
    float tw = q4.w * q4.w / s4.w;
    float tsum = tx + ty + tz + tw;
    #pragma unroll
    for (int m = 1; m < 64; m <<= 1) tsum += __shfl_xor(tsum, m);
    // argmax (first-occurrence tie semantics like jnp.argmax)
    float mv = tx; int mi = lane * 4;
    if (ty > mv) { mv = ty; mi = lane * 4 + 1; }
    if (tz > mv) { mv = tz; mi = lane * 4 + 2; }
    if (tw > mv) { mv = tw; mi = lane * 4 + 3; }
    #pragma unroll
    for (int m = 1; m < 64; m <<= 1) {
        float ov = __shfl_xor(mv, m);
        int   oi = __shfl_xor(mi, m);
        if (ov > mv || (ov == mv && oi < mi)) { mv = ov; mi = oi; }
    }
    // relu(v-0.1)+sign(.)*0.1 == (v > 0.1 ? v : 0)
    float wgt = mv / tsum;
    if (wgt > 0.1f) {
        if (lane == 0) atomicAdd(&denom[mi], wgt);
        const float4* xr = (const float4*)(x + (size_t)row * DIM);
        #pragma unroll
        for (int i = 0; i < 4; i++) {
            float4 xv = xr[lane + i * 64];
            int base = mi * DIM + (lane + i * 64) * 4;
            atomicAdd(&numer[base + 0], wgt * xv.x);
            atomicAdd(&numer[base + 1], wgt * xv.y);
            atomicAdd(&numer[base + 2], wgt * xv.z);
            atomicAdd(&numer[base + 3], wgt * xv.w);
        }
    }
}

// ---------------- P3: new_clusters = numer / (denom + eps) ----------------
__global__ __launch_bounds__(256)
void finalize(const float* __restrict__ numer, const float* __restrict__ denom,
              float* __restrict__ outc) {
    const int i = blockIdx.x * 256 + threadIdx.x;   // float4 index, 0..65535
    float4 nv = ((const float4*)numer)[i];
    float dd = denom[i >> 8] + 2.220446049250313e-16f;  // np.finfo(float).eps
    float4 r;
    r.x = nv.x / dd; r.y = nv.y / dd; r.z = nv.z / dd; r.w = nv.w / dd;
    ((float4*)outc)[i] = r;
}

extern "C" void kernel_launch(void* const* d_in, const int* in_sizes, int n_in,
                              void* d_out, int out_size, void* d_ws, size_t ws_size,
                              hipStream_t stream) {
    const float* x        = (const float*)d_in[0];
    const float* clusters = (const float*)d_in[1];
    float* out      = (float*)d_out;
    float* q_out    = out;                               // [N, K]
    float* out_clus = out + (size_t)N_ROWS * KCL;        // [K, D]

    // workspace layout
    float*  numer = (float*)d_ws;                        // K*D floats (1 MB)
    float*  q_sum = numer + (size_t)KCL * DIM;           // K
    float*  denom = q_sum + KCL;                         // K
    float*  c_sq  = denom + KCL;                         // K
    bf16_t* cb    = (bf16_t*)(c_sq + KCL);               // K*D bf16 (512 KB)

    // zero the atomically-accumulated buffers (ws is re-poisoned before each call)
    hipMemsetAsync(numer, 0, ((size_t)KCL * DIM + 2 * KCL) * sizeof(float), stream);

    prep_clusters<<<KCL, 256, 0, stream>>>(clusters, cb, c_sq);
    gemm_q<<<N_ROWS / 128, 512, 0, stream>>>(x, cb, c_sq, q_out, q_sum);
    sharpen_scatter<<<N_ROWS / 4, 256, 0, stream>>>(q_out, q_sum, x, numer, denom);
    finalize<<<256, 256, 0, stream>>>(numer, denom, out_clus);
}

// Round 2
// 419.035 us; speedup vs baseline: 1.0362x; 1.0362x over previous
//
#include <hip/hip_runtime.h>

#define N_ROWS 65536
#define DIM    1024
#define KCL    256

typedef __bf16 bf16_t;
typedef __attribute__((ext_vector_type(8))) __bf16 bf16x8;
typedef __attribute__((ext_vector_type(4))) __bf16 bf16x4;
typedef __attribute__((ext_vector_type(4))) float  floatx4;

// ---------------- P0: clusters -> bf16, c_sq, zero accumulators ----------------
__global__ __launch_bounds__(256)
void prep_clusters(const float* __restrict__ clusters,
                   bf16_t* __restrict__ cb, float* __restrict__ c_sq,
                   float* __restrict__ numer, float* __restrict__ q_sum,
                   float* __restrict__ denom) {
    const int k = blockIdx.x;     // 0..255
    const int t = threadIdx.x;    // 0..255
    const float4 v = ((const float4*)(clusters + (size_t)k * DIM))[t];
    bf16x4 b;
    b[0] = (bf16_t)v.x; b[1] = (bf16_t)v.y; b[2] = (bf16_t)v.z; b[3] = (bf16_t)v.w;
    *(bf16x4*)(cb + (size_t)k * DIM + t * 4) = b;
    // zero numer row k (ws is poisoned 0xAA each call)
    float4 z = {0.f, 0.f, 0.f, 0.f};
    ((float4*)(numer + (size_t)k * DIM))[t] = z;
    float s = v.x*v.x + v.y*v.y + v.z*v.z + v.w*v.w;
    #pragma unroll
    for (int m = 1; m < 64; m <<= 1) s += __shfl_xor(s, m);
    __shared__ float ps[4];
    if ((t & 63) == 0) ps[t >> 6] = s;
    __syncthreads();
    if (t == 0) {
        c_sq[k] = ps[0] + ps[1] + ps[2] + ps[3];
        q_sum[k] = 0.f;
        denom[k] = 0.f;
    }
}

// ---------------- P1: GEMM + q epilogue ----------------
// 512 threads = 8 waves, tile 128(M) x 256(N = all K clusters), BK=64.
// Wave w: rows (w>>2)*64..+64, cols (w&3)*64..+64 -> 4x4 tiles of 16x16x32 MFMA.
// __launch_bounds__(512,4): force VGPR<=128 so 2 blocks/CU (16 waves) fit.
__global__ __launch_bounds__(512, 4)
void gemm_q(const float* __restrict__ x, const bf16_t* __restrict__ cb,
            const float* __restrict__ c_sq, float* __restrict__ q_out,
            float* __restrict__ q_sum) {
    __shared__ bf16_t As[128 * 72];   // stride 72: bank-conflict break
    __shared__ bf16_t Bs[256 * 72];
    __shared__ float  xsq[128];
    __shared__ float  rowsum[128];
    __shared__ float  colsum[256];

    const int tid  = threadIdx.x;
    const int lane = tid & 63;
    const int w    = tid >> 6;          // 0..7
    const int l15  = lane & 15;
    const int quad = lane >> 4;         // 0..3
    const int wm   = (w >> 2) * 64;     // 0 or 64
    const int wn   = (w & 3) * 64;      // 0,64,128,192
    const int block_row = blockIdx.x * 128;

    if (tid < 128) rowsum[tid] = 0.f;
    if (tid < 256) colsum[tid] = 0.f;

    // Staging assignment: 8-element chunks. A: rows ar0 and ar0+64; B: rows ar0+i*64.
    const int ar0 = tid >> 3;           // 0..63
    const int ac8 = tid & 7;            // chunk within row
    const float*  aptr0 = x  + (size_t)(block_row + ar0) * DIM + ac8 * 8;
    const float*  aptr1 = aptr0 + (size_t)64 * DIM;
    const bf16_t* bptr  = cb + (size_t)ar0 * DIM + ac8 * 8;

    float xp0 = 0.f, xp1 = 0.f;         // private ||x||^2 partials (2 fixed rows)

    floatx4 acc[4][4];
    #pragma unroll
    for (int i = 0; i < 4; i++)
        #pragma unroll
        for (int j = 0; j < 4; j++) {
            floatx4 zz = {0.f, 0.f, 0.f, 0.f};
            acc[i][j] = zz;
        }

    __syncthreads();

    for (int kb = 0; kb < 16; ++kb) {
        const int k0 = kb * 64;
        // --- global loads (issue all; MLP) ---
        float4 a00 = *(const float4*)(aptr0 + k0);
        float4 a01 = *(const float4*)(aptr0 + k0 + 4);
        float4 a10 = *(const float4*)(aptr1 + k0);
        float4 a11 = *(const float4*)(aptr1 + k0 + 4);
        bf16x8 bv[4];
        #pragma unroll
        for (int i = 0; i < 4; i++)
            bv[i] = *(const bf16x8*)(bptr + (size_t)i * 64 * DIM + k0);
        // --- private xsq accumulation (fp32) ---
        xp0 += a00.x*a00.x + a00.y*a00.y + a00.z*a00.z + a00.w*a00.w
             + a01.x*a01.x + a01.y*a01.y + a01.z*a01.z + a01.w*a01.w;
        xp1 += a10.x*a10.x + a10.y*a10.y + a10.z*a10.z + a10.w*a10.w
             + a11.x*a11.x + a11.y*a11.y + a11.z*a11.z + a11.w*a11.w;
        // --- convert + LDS writes (16B each) ---
        bf16x8 ab0, ab1;
        ab0[0]=(bf16_t)a00.x; ab0[1]=(bf16_t)a00.y; ab0[2]=(bf16_t)a00.z; ab0[3]=(bf16_t)a00.w;
        ab0[4]=(bf16_t)a01.x; ab0[5]=(bf16_t)a01.y; ab0[6]=(bf16_t)a01.z; ab0[7]=(bf16_t)a01.w;
        ab1[0]=(bf16_t)a10.x; ab1[1]=(bf16_t)a10.y; ab1[2]=(bf16_t)a10.z; ab1[3]=(bf16_t)a10.w;
        ab1[4]=(bf16_t)a11.x; ab1[5]=(bf16_t)a11.y; ab1[6]=(bf16_t)a11.z; ab1[7]=(bf16_t)a11.w;
        *(bf16x8*)(As + ar0 * 72 + ac8 * 8)        = ab0;
        *(bf16x8*)(As + (ar0 + 64) * 72 + ac8 * 8) = ab1;
        #pragma unroll
        for (int i = 0; i < 4; i++)
            *(bf16x8*)(Bs + (ar0 + i * 64) * 72 + ac8 * 8) = bv[i];
        __syncthreads();
        // --- MFMA: 2 k-steps, af[4] resident, bf streamed per-nt (20 frag VGPRs) ---
        #pragma unroll
        for (int kk = 0; kk < 2; ++kk) {
            bf16x8 af[4];
            #pragma unroll
            for (int mt = 0; mt < 4; ++mt)
                af[mt] = *(bf16x8*)(As + (wm + mt * 16 + l15) * 72 + kk * 32 + quad * 8);
            #pragma unroll
            for (int nt = 0; nt < 4; ++nt) {
                bf16x8 bfv = *(bf16x8*)(Bs + (wn + nt * 16 + l15) * 72 + kk * 32 + quad * 8);
                #pragma unroll
                for (int mt = 0; mt < 4; ++mt)
                    acc[mt][nt] = __builtin_amdgcn_mfma_f32_16x16x32_bf16(
                        af[mt], bfv, acc[mt][nt], 0, 0, 0);
            }
        }
        __syncthreads();
    }

    // ---- one-time xsq reduction (8 lanes share a row) ----
    xp0 += __shfl_xor(xp0, 1); xp0 += __shfl_xor(xp0, 2); xp0 += __shfl_xor(xp0, 4);
    xp1 += __shfl_xor(xp1, 1); xp1 += __shfl_xor(xp1, 2); xp1 += __shfl_xor(xp1, 4);
    if ((lane & 7) == 0) { xsq[ar0] = xp0; xsq[ar0 + 64] = xp1; }
    __syncthreads();

    // ---- epilogue: dist -> q_un -> row-normalize -> store + column sums ----
    float csq_v[4];
    #pragma unroll
    for (int nt = 0; nt < 4; nt++) csq_v[nt] = c_sq[wn + nt * 16 + l15];
    floatx4 xs4[4];
    #pragma unroll
    for (int mt = 0; mt < 4; mt++)
        xs4[mt] = *(floatx4*)(xsq + wm + mt * 16 + quad * 4);

    #pragma unroll
    for (int mt = 0; mt < 4; mt++) {
        floatx4 rps = {0.f, 0.f, 0.f, 0.f};
        #pragma unroll
        for (int nt = 0; nt < 4; nt++) {
            #pragma unroll
            for (int r = 0; r < 4; r++) {
                float d  = xs4[mt][r] + csq_v[nt] - 2.0f * acc[mt][nt][r];
                float qv = 1.0f / (1.0f + d);   // ALPHA = 1
                acc[mt][nt][r] = qv;
                rps[r] += qv;
            }
        }
        #pragma unroll
        for (int m = 1; m < 16; m <<= 1) {
            rps[0] += __shfl_xor(rps[0], m);
            rps[1] += __shfl_xor(rps[1], m);
            rps[2] += __shfl_xor(rps[2], m);
            rps[3] += __shfl_xor(rps[3], m);
        }
        if (l15 == 0) {
            #pragma unroll
            for (int r = 0; r < 4; r++)
                atomicAdd(&rowsum[wm + mt * 16 + quad * 4 + r], rps[r]);
        }
    }
    __syncthreads();

    float colp[4] = {0.f, 0.f, 0.f, 0.f};
    #pragma unroll
    for (int mt = 0; mt < 4; mt++) {
        floatx4 rs4 = *(floatx4*)(rowsum + wm + mt * 16 + quad * 4);
        floatx4 inv;
        #pragma unroll
        for (int r = 0; r < 4; r++) inv[r] = 1.0f / rs4[r];
        #pragma unroll
        for (int nt = 0; nt < 4; nt++) {
            #pragma unroll
            for (int r = 0; r < 4; r++) {
                float qn = acc[mt][nt][r] * inv[r];
                q_out[(size_t)(block_row + wm + mt * 16 + quad * 4 + r) * KCL
                      + wn + nt * 16 + l15] = qn;
                colp[nt] += qn;
            }
        }
    }
    #pragma unroll
    for (int nt = 0; nt < 4; nt++) {
        colp[nt] += __shfl_xor(colp[nt], 16);
        colp[nt] += __shfl_xor(colp[nt], 32);
    }
    if (lane < 16) {
        #pragma unroll
        for (int nt = 0; nt < 4; nt++)
            atomicAdd(&colsum[wn + nt * 16 + l15], colp[nt]);
    }
    __syncthreads();
    if (tid < 256) atomicAdd(&q_sum[tid], colsum[tid]);
}

// ---------------- P2: sharpen + threshold + scatter ----------------
__global__ __launch_bounds__(256)
void sharpen_scatter(const float* __restrict__ q, const float* __restrict__ q_sum,
                     const float* __restrict__ x,
                     float* __restrict__ numer, float* __restrict__ denom) {
    const int tid  = threadIdx.x;
    const int lane = tid & 63;
    const int row  = blockIdx.x * 4 + (tid >> 6);
    const float4 q4 = ((const float4*)(q + (size_t)row * KCL))[lane];
    const float4 s4 = ((const float4*)q_sum)[lane];
    float tx = q4.x * q4.x / s4.x;
    float ty = q4.y * q4.y / s4.y;
    float tz = q4.z * q4.z / s4.z;
    float tw = q4.w * q4.w / s4.w;
    float tsum = tx + ty + tz + tw;
    #pragma unroll
    for (int m = 1; m < 64; m <<= 1) tsum += __shfl_xor(tsum, m);
    // argmax (first-occurrence tie semantics like jnp.argmax)
    float mv = tx; int mi = lane * 4;
    if (ty > mv) { mv = ty; mi = lane * 4 + 1; }
    if (tz > mv) { mv = tz; mi = lane * 4 + 2; }
    if (tw > mv) { mv = tw; mi = lane * 4 + 3; }
    #pragma unroll
    for (int m = 1; m < 64; m <<= 1) {
        float ov = __shfl_xor(mv, m);
        int   oi = __shfl_xor(mi, m);
        if (ov > mv || (ov == mv && oi < mi)) { mv = ov; mi = oi; }
    }
    // relu(v-0.1)+sign(.)*0.1 == (v > 0.1 ? v : 0)
    float wgt = mv / tsum;
    if (wgt > 0.1f) {
        if (lane == 0) atomicAdd(&denom[mi], wgt);
        const float4* xr = (const float4*)(x + (size_t)row * DIM);
        #pragma unroll
        for (int i = 0; i < 4; i++) {
            float4 xv = xr[lane + i * 64];
            int base = mi * DIM + (lane + i * 64) * 4;
            atomicAdd(&numer[base + 0], wgt * xv.x);
            atomicAdd(&numer[base + 1], wgt * xv.y);
            atomicAdd(&numer[base + 2], wgt * xv.z);
            atomicAdd(&numer[base + 3], wgt * xv.w);
        }
    }
}

// ---------------- P3: new_clusters = numer / (denom + eps) ----------------
__global__ __launch_bounds__(256)
void finalize(const float* __restrict__ numer, const float* __restrict__ denom,
              float* __restrict__ outc) {
    const int i = blockIdx.x * 256 + threadIdx.x;   // float4 index, 0..65535
    float4 nv = ((const float4*)numer)[i];
    float dd = denom[i >> 8] + 2.220446049250313e-16f;  // np.finfo(float).eps
    float4 r;
    r.x = nv.x / dd; r.y = nv.y / dd; r.z = nv.z / dd; r.w = nv.w / dd;
    ((float4*)outc)[i] = r;
}

extern "C" void kernel_launch(void* const* d_in, const int* in_sizes, int n_in,
                              void* d_out, int out_size, void* d_ws, size_t ws_size,
                              hipStream_t stream) {
    const float* x        = (const float*)d_in[0];
    const float* clusters = (const float*)d_in[1];
    float* out      = (float*)d_out;
    float* q_out    = out;                               // [N, K]
    float* out_clus = out + (size_t)N_ROWS * KCL;        // [K, D]

    // workspace layout
    float*  numer = (float*)d_ws;                        // K*D floats (1 MB)
    float*  q_sum = numer + (size_t)KCL * DIM;           // K
    float*  denom = q_sum + KCL;                         // K
    float*  c_sq  = denom + KCL;                         // K
    bf16_t* cb    = (bf16_t*)(c_sq + KCL);               // K*D bf16 (512 KB)

    prep_clusters<<<KCL, 256, 0, stream>>>(clusters, cb, c_sq, numer, q_sum, denom);
    gemm_q<<<N_ROWS / 128, 512, 0, stream>>>(x, cb, c_sq, q_out, q_sum);
    sharpen_scatter<<<N_ROWS / 4, 256, 0, stream>>>(q_out, q_sum, x, numer, denom);
    finalize<<<256, 256, 0, stream>>>(numer, denom, out_clus);
}

// Round 3
// 409.142 us; speedup vs baseline: 1.0613x; 1.0242x over previous
//
#include <hip/hip_runtime.h>

#define N_ROWS 65536
#define DIM    1024
#define KCL    256

typedef __bf16 bf16_t;
typedef __attribute__((ext_vector_type(8))) __bf16 bf16x8;
typedef __attribute__((ext_vector_type(4))) __bf16 bf16x4;
typedef __attribute__((ext_vector_type(4))) float  floatx4;

// ---------------- P0: clusters -> bf16, c_sq, zero accumulators ----------------
__global__ __launch_bounds__(256)
void prep_clusters(const float* __restrict__ clusters,
                   bf16_t* __restrict__ cb, float* __restrict__ c_sq,
                   float* __restrict__ numer, float* __restrict__ q_sum,
                   float* __restrict__ denom) {
    const int k = blockIdx.x;     // 0..255
    const int t = threadIdx.x;    // 0..255
    const float4 v = ((const float4*)(clusters + (size_t)k * DIM))[t];
    bf16x4 b;
    b[0] = (bf16_t)v.x; b[1] = (bf16_t)v.y; b[2] = (bf16_t)v.z; b[3] = (bf16_t)v.w;
    *(bf16x4*)(cb + (size_t)k * DIM + t * 4) = b;
    // zero numer row k (ws is poisoned 0xAA each call)
    float4 z = {0.f, 0.f, 0.f, 0.f};
    ((float4*)(numer + (size_t)k * DIM))[t] = z;
    float s = v.x*v.x + v.y*v.y + v.z*v.z + v.w*v.w;
    #pragma unroll
    for (int m = 1; m < 64; m <<= 1) s += __shfl_xor(s, m);
    __shared__ float ps[4];
    if ((t & 63) == 0) ps[t >> 6] = s;
    __syncthreads();
    if (t == 0) {
        c_sq[k] = ps[0] + ps[1] + ps[2] + ps[3];
        q_sum[k] = 0.f;
        denom[k] = 0.f;
    }
}

// ---------------- P1: GEMM + q epilogue ----------------
// 512 threads = 8 waves, tile 64(M) x 256(N = all K clusters), BK=64.
// Wave w covers cols w*32..w*32+31 for all 64 rows: acc[4][2] = 32 VGPR.
// Register double-buffer: next iter's global loads issued before current MFMA.
__global__ __launch_bounds__(512, 4)
void gemm_q(const float* __restrict__ x, const bf16_t* __restrict__ cb,
            const float* __restrict__ c_sq, float* __restrict__ q_out,
            float* __restrict__ q_sum) {
    __shared__ __align__(16) bf16_t As[64 * 72];    // stride 72: conflict-optimal
    __shared__ __align__(16) bf16_t Bs[256 * 72];
    __shared__ float xsq[64];
    __shared__ float rowsum[64];

    const int tid  = threadIdx.x;
    const int lane = tid & 63;
    const int w    = tid >> 6;          // 0..7
    const int l15  = lane & 15;
    const int quad = lane >> 4;         // 0..3
    const int wn   = w * 32;            // wave's 32-col strip
    const int block_row = blockIdx.x * 64;

    if (tid < 64) rowsum[tid] = 0.f;

    // Staging: thread owns 8 consecutive floats of one A row + 4 B rows.
    const int ar  = tid >> 3;           // 0..63
    const int ac8 = tid & 7;
    const float*  aptr = x  + (size_t)(block_row + ar) * DIM + ac8 * 8;
    const bf16_t* bptr = cb + (size_t)ar * DIM + ac8 * 8;

    float xp = 0.f;                     // private ||x||^2 partial (one fixed row)

    floatx4 acc[4][2];
    #pragma unroll
    for (int i = 0; i < 4; i++)
        #pragma unroll
        for (int j = 0; j < 2; j++) {
            floatx4 zz = {0.f, 0.f, 0.f, 0.f};
            acc[i][j] = zz;
        }

    // preload kb = 0
    float4 a0 = *(const float4*)(aptr);
    float4 a1 = *(const float4*)(aptr + 4);
    bf16x8 bv[4];
    #pragma unroll
    for (int i = 0; i < 4; i++)
        bv[i] = *(const bf16x8*)(bptr + (size_t)i * 64 * DIM);

    __syncthreads();                    // covers rowsum init

    for (int kb = 0; kb < 16; ++kb) {
        // --- issue NEXT iteration's global loads first (latency overlap) ---
        float4 a0n = a0, a1n = a1;
        bf16x8 bvn[4] = {bv[0], bv[1], bv[2], bv[3]};
        if (kb < 15) {
            const int k1 = (kb + 1) * 64;
            a0n = *(const float4*)(aptr + k1);
            a1n = *(const float4*)(aptr + k1 + 4);
            #pragma unroll
            for (int i = 0; i < 4; i++)
                bvn[i] = *(const bf16x8*)(bptr + (size_t)i * 64 * DIM + k1);
        }
        // --- xsq from current regs ---
        xp += a0.x*a0.x + a0.y*a0.y + a0.z*a0.z + a0.w*a0.w
            + a1.x*a1.x + a1.y*a1.y + a1.z*a1.z + a1.w*a1.w;
        // --- convert + LDS writes (current) ---
        bf16x8 ab;
        ab[0]=(bf16_t)a0.x; ab[1]=(bf16_t)a0.y; ab[2]=(bf16_t)a0.z; ab[3]=(bf16_t)a0.w;
        ab[4]=(bf16_t)a1.x; ab[5]=(bf16_t)a1.y; ab[6]=(bf16_t)a1.z; ab[7]=(bf16_t)a1.w;
        *(bf16x8*)(As + ar * 72 + ac8 * 8) = ab;
        #pragma unroll
        for (int i = 0; i < 4; i++)
            *(bf16x8*)(Bs + (ar + i * 64) * 72 + ac8 * 8) = bv[i];
        __syncthreads();
        // --- MFMA: 2 k-steps x (4 mt x 2 nt) ---
        #pragma unroll
        for (int kk = 0; kk < 2; ++kk) {
            bf16x8 af[4];
            #pragma unroll
            for (int mt = 0; mt < 4; ++mt)
                af[mt] = *(bf16x8*)(As + (mt * 16 + l15) * 72 + kk * 32 + quad * 8);
            #pragma unroll
            for (int nt = 0; nt < 2; ++nt) {
                bf16x8 bfv = *(bf16x8*)(Bs + (wn + nt * 16 + l15) * 72 + kk * 32 + quad * 8);
                #pragma unroll
                for (int mt = 0; mt < 4; ++mt)
                    acc[mt][nt] = __builtin_amdgcn_mfma_f32_16x16x32_bf16(
                        af[mt], bfv, acc[mt][nt], 0, 0, 0);
            }
        }
        __syncthreads();
        // --- rotate register buffers ---
        a0 = a0n; a1 = a1n;
        #pragma unroll
        for (int i = 0; i < 4; i++) bv[i] = bvn[i];
    }

    // ---- one-time xsq reduction (8 lanes share a row) ----
    xp += __shfl_xor(xp, 1); xp += __shfl_xor(xp, 2); xp += __shfl_xor(xp, 4);
    if ((lane & 7) == 0) xsq[ar] = xp;
    __syncthreads();

    // ---- epilogue: dist -> q_un -> row-normalize -> store + column sums ----
    float csq_v[2];
    #pragma unroll
    for (int nt = 0; nt < 2; nt++) csq_v[nt] = c_sq[wn + nt * 16 + l15];
    floatx4 xs4[4];
    #pragma unroll
    for (int mt = 0; mt < 4; mt++)
        xs4[mt] = *(floatx4*)(xsq + mt * 16 + quad * 4);

    #pragma unroll
    for (int mt = 0; mt < 4; mt++) {
        floatx4 rps = {0.f, 0.f, 0.f, 0.f};
        #pragma unroll
        for (int nt = 0; nt < 2; nt++) {
            #pragma unroll
            for (int r = 0; r < 4; r++) {
                float d  = xs4[mt][r] + csq_v[nt] - 2.0f * acc[mt][nt][r];
                float qv = 1.0f / (1.0f + d);   // ALPHA = 1
                acc[mt][nt][r] = qv;
                rps[r] += qv;
            }
        }
        // reduce over the 16 l15 lanes (within quad)
        #pragma unroll
        for (int m = 1; m < 16; m <<= 1) {
            rps[0] += __shfl_xor(rps[0], m);
            rps[1] += __shfl_xor(rps[1], m);
            rps[2] += __shfl_xor(rps[2], m);
            rps[3] += __shfl_xor(rps[3], m);
        }
        if (l15 == 0) {
            #pragma unroll
            for (int r = 0; r < 4; r++)
                atomicAdd(&rowsum[mt * 16 + quad * 4 + r], rps[r]);
        }
    }
    __syncthreads();

    float colp[2] = {0.f, 0.f};
    #pragma unroll
    for (int mt = 0; mt < 4; mt++) {
        floatx4 rs4 = *(floatx4*)(rowsum + mt * 16 + quad * 4);
        floatx4 inv;
        #pragma unroll
        for (int r = 0; r < 4; r++) inv[r] = 1.0f / rs4[r];
        #pragma unroll
        for (int nt = 0; nt < 2; nt++) {
            #pragma unroll
            for (int r = 0; r < 4; r++) {
                float qn = acc[mt][nt][r] * inv[r];
                q_out[(size_t)(block_row + mt * 16 + quad * 4 + r) * KCL
                      + wn + nt * 16 + l15] = qn;
                colp[nt] += qn;
            }
        }
    }
    // wave owns distinct 32-col strip: reduce over quad, add straight to global
    #pragma unroll
    for (int nt = 0; nt < 2; nt++) {
        colp[nt] += __shfl_xor(colp[nt], 16);
        colp[nt] += __shfl_xor(colp[nt], 32);
    }
    if (lane < 16) {
        atomicAdd(&q_sum[wn + l15], colp[0]);
        atomicAdd(&q_sum[wn + 16 + l15], colp[1]);
    }
}

// ---------------- P2: sharpen + threshold + scatter ----------------
__global__ __launch_bounds__(256)
void sharpen_scatter(const float* __restrict__ q, const float* __restrict__ q_sum,
                     const float* __restrict__ x,
                     float* __restrict__ numer, float* __restrict__ denom) {
    const int tid  = threadIdx.x;
    const int lane = tid & 63;
    const int row  = blockIdx.x * 4 + (tid >> 6);
    const float4 q4 = ((const float4*)(q + (size_t)row * KCL))[lane];
    const float4 s4 = ((const float4*)q_sum)[lane];
    float tx = q4.x * q4.x / s4.x;
    float ty = q4.y * q4.y / s4.y;
    float tz = q4.z * q4.z / s4.z;
    float tw = q4.w * q4.w / s4.w;
    float tsum = tx + ty + tz + tw;
    #pragma unroll
    for (int m = 1; m < 64; m <<= 1) tsum += __shfl_xor(tsum, m);
    // argmax (first-occurrence tie semantics like jnp.argmax)
    float mv = tx; int mi = lane * 4;
    if (ty > mv) { mv = ty; mi = lane * 4 + 1; }
    if (tz > mv) { mv = tz; mi = lane * 4 + 2; }
    if (tw > mv) { mv = tw; mi = lane * 4 + 3; }
    #pragma unroll
    for (int m = 1; m < 64; m <<= 1) {
        float ov = __shfl_xor(mv, m);
        int   oi = __shfl_xor(mi, m);
        if (ov > mv || (ov == mv && oi < mi)) { mv = ov; mi = oi; }
    }
    // relu(v-0.1)+sign(.)*0.1 == (v > 0.1 ? v : 0)
    float wgt = mv / tsum;
    if (wgt > 0.1f) {
        if (lane == 0) atomicAdd(&denom[mi], wgt);
        const float4* xr = (const float4*)(x + (size_t)row * DIM);
        #pragma unroll
        for (int i = 0; i < 4; i++) {
            float4 xv = xr[lane + i * 64];
            int base = mi * DIM + (lane + i * 64) * 4;
            atomicAdd(&numer[base + 0], wgt * xv.x);
            atomicAdd(&numer[base + 1], wgt * xv.y);
            atomicAdd(&numer[base + 2], wgt * xv.z);
            atomicAdd(&numer[base + 3], wgt * xv.w);
        }
    }
}

// ---------------- P3: new_clusters = numer / (denom + eps) ----------------
__global__ __launch_bounds__(256)
void finalize(const float* __restrict__ numer, const float* __restrict__ denom,
              float* __restrict__ outc) {
    const int i = blockIdx.x * 256 + threadIdx.x;   // float4 index, 0..65535
    float4 nv = ((const float4*)numer)[i];
    float dd = denom[i >> 8] + 2.220446049250313e-16f;  // np.finfo(float).eps
    float4 r;
    r.x = nv.x / dd; r.y = nv.y / dd; r.z = nv.z / dd; r.w = nv.w / dd;
    ((float4*)outc)[i] = r;
}

extern "C" void kernel_launch(void* const* d_in, const int* in_sizes, int n_in,
                              void* d_out, int out_size, void* d_ws, size_t ws_size,
                              hipStream_t stream) {
    const float* x        = (const float*)d_in[0];
    const float* clusters = (const float*)d_in[1];
    float* out      = (float*)d_out;
    float* q_out    = out;                               // [N, K]
    float* out_clus = out + (size_t)N_ROWS * KCL;        // [K, D]

    // workspace layout
    float*  numer = (float*)d_ws;                        // K*D floats (1 MB)
    float*  q_sum = numer + (size_t)KCL * DIM;           // K
    float*  denom = q_sum + KCL;                         // K
    float*  c_sq  = denom + KCL;                         // K
    bf16_t* cb    = (bf16_t*)(c_sq + KCL);               // K*D bf16 (512 KB)

    prep_clusters<<<KCL, 256, 0, stream>>>(clusters, cb, c_sq, numer, q_sum, denom);
    gemm_q<<<N_ROWS / 64, 512, 0, stream>>>(x, cb, c_sq, q_out, q_sum);
    sharpen_scatter<<<N_ROWS / 4, 256, 0, stream>>>(q_out, q_sum, x, numer, denom);
    finalize<<<256, 256, 0, stream>>>(numer, denom, out_clus);
}